// Round 1
// baseline (1743.884 us; speedup 1.0000x reference)
//
#include <hip/hip_runtime.h>
#include <cmath>

#define NN 50000
#define EE 600000

__device__ __forceinline__ float softplus_f(float x) {
  // stable: max(x,0) + log1p(exp(-|x|))  == log(1+exp(x))
  return fmaxf(x, 0.f) + log1pf(__expf(-fabsf(x)));
}
__device__ __forceinline__ float sigmoid_f(float x) {
  return 1.f / (1.f + __expf(-x));
}

// ---------------- zero: d_out (aggr accumulator) + stats doubles ----------------
__global__ __launch_bounds__(256) void zero_kernel(float4* aggr4, float* stats_f) {
  int i = blockIdx.x * 256 + threadIdx.x;
  int stride = gridDim.x * 256;
  const int n4 = NN * 32;  // NN*128/4
  float4 z = make_float4(0.f, 0.f, 0.f, 0.f);
  for (int k = i; k < n4; k += stride) aggr4[k] = z;
  if (i < 512) stats_f[i] = 0.f;  // 256 doubles
}

// ---------------- GEMM: C[64 rows,128] = act(A@B + bias), K=128 in 2 chunks ----
template <bool ACT, bool HASBIAS>
__global__ __launch_bounds__(256) void gemm128(const float* __restrict__ A,
                                               const float* __restrict__ B,
                                               const float* __restrict__ bias,
                                               float* __restrict__ Cmat,
                                               int nrows) {
  __shared__ float Ash[64][68];   // pad 64->68: 272B row, float4-aligned, banks ok
  __shared__ float Bsh[64][128];
  const int tid = threadIdx.x;
  const int row0 = blockIdx.x * 64;
  const int tx = tid & 15, ty = tid >> 4;
  const int r0 = ty * 4, c0 = tx * 4;

  float acc[4][8];
#pragma unroll
  for (int r = 0; r < 4; ++r)
#pragma unroll
    for (int j = 0; j < 8; ++j) acc[r][j] = 0.f;

  for (int kb = 0; kb < 2; ++kb) {
    // stage A chunk (64 rows x 64 k)
    for (int i = tid; i < 64 * 16; i += 256) {
      int r = i >> 4, k4 = i & 15;
      int gr = row0 + r; if (gr >= nrows) gr = nrows - 1;
      float4 v = ((const float4*)(A + (size_t)gr * 128 + kb * 64))[k4];
      *(float4*)&Ash[r][k4 * 4] = v;
    }
    // stage B chunk (64 k x 128 cols)
    for (int i = tid; i < 64 * 32; i += 256) {
      int k = i >> 5, c4 = i & 31;
      float4 v = ((const float4*)(B + (size_t)(kb * 64 + k) * 128))[c4];
      *(float4*)&Bsh[k][c4 * 4] = v;
    }
    __syncthreads();
#pragma unroll 4
    for (int k = 0; k < 64; ++k) {
      float aa[4] = {Ash[r0 + 0][k], Ash[r0 + 1][k], Ash[r0 + 2][k], Ash[r0 + 3][k]};
      float4 b0 = *(const float4*)&Bsh[k][c0];
      float4 b1 = *(const float4*)&Bsh[k][c0 + 64];
      float bb[8] = {b0.x, b0.y, b0.z, b0.w, b1.x, b1.y, b1.z, b1.w};
#pragma unroll
      for (int r = 0; r < 4; ++r)
#pragma unroll
        for (int j = 0; j < 8; ++j) acc[r][j] = fmaf(aa[r], bb[j], acc[r][j]);
    }
    __syncthreads();
  }

  float bv[8];
#pragma unroll
  for (int j = 0; j < 8; ++j)
    bv[j] = HASBIAS ? bias[j < 4 ? c0 + j : c0 + 60 + j] : 0.f;  // c0+64+(j-4)
#pragma unroll
  for (int r = 0; r < 4; ++r) {
    int gr = row0 + r0 + r;
    if (gr < nrows) {
      float tmp[8];
#pragma unroll
      for (int j = 0; j < 8; ++j) {
        float v = acc[r][j] + bv[j];
        tmp[j] = ACT ? softplus_f(v) : v;
      }
      *(float4*)(Cmat + (size_t)gr * 128 + c0) = make_float4(tmp[0], tmp[1], tmp[2], tmp[3]);
      *(float4*)(Cmat + (size_t)gr * 128 + c0 + 64) = make_float4(tmp[4], tmp[5], tmp[6], tmp[7]);
    }
  }
}

// ---------------- e = softplus(edge_attr @ Wsh + bsh), 16 lanes per edge -------
__global__ __launch_bounds__(256) void edge_e_kernel(const float* __restrict__ edge_attr,
                                                     const float* __restrict__ Wsh,
                                                     const float* __restrict__ bsh,
                                                     float* __restrict__ ebuf) {
  __shared__ float wsh[128];
  int tid = threadIdx.x;
  if (tid < 128) wsh[tid] = Wsh[tid];
  __syncthreads();
  int wave = tid >> 6, lane = tid & 63;
  int sub = lane >> 4, l16 = lane & 15;
  int edge = (blockIdx.x * 4 + wave) * 4 + sub;
  const float4* row = (const float4*)(edge_attr + (size_t)edge * 128);
  float4 v0 = row[l16], v1 = row[l16 + 16];
  float4 w0 = *(const float4*)&wsh[l16 * 4];
  float4 w1 = *(const float4*)&wsh[64 + l16 * 4];
  float p = v0.x * w0.x + v0.y * w0.y + v0.z * w0.z + v0.w * w0.w +
            v1.x * w1.x + v1.y * w1.y + v1.z * w1.z + v1.w * w1.w;
  p += __shfl_xor(p, 1);
  p += __shfl_xor(p, 2);
  p += __shfl_xor(p, 4);
  p += __shfl_xor(p, 8);
  if (l16 == 0) ebuf[edge] = softplus_f(p + bsh[0]);
}

// ---------------- per-edge gate*core + atomic segment-sum into aggr ------------
__global__ __launch_bounds__(256) void edge_msg_kernel(const int* __restrict__ eidx,
                                                       const float* __restrict__ ebuf,
                                                       const float* __restrict__ P,
                                                       const float* __restrict__ Wf_e,
                                                       const float* __restrict__ Ws_e,
                                                       float* __restrict__ aggr) {
  __shared__ float wfe[128], wse[128];
  int tid = threadIdx.x;
  if (tid < 128) wfe[tid] = Wf_e[tid];
  else wse[tid - 128] = Ws_e[tid - 128];
  __syncthreads();
  int eloc = tid >> 5, lane = tid & 31;
  int edge = blockIdx.x * 8 + eloc;
  int src = eidx[edge];
  int dst = eidx[EE + edge];
  float eV = ebuf[edge];
  const size_t NC = (size_t)NN * 128;
  const float4* pif = (const float4*)(P + (size_t)dst * 128);
  const float4* pjf = (const float4*)(P + NC + (size_t)src * 128);
  const float4* pis = (const float4*)(P + NC * 2 + (size_t)dst * 128);
  const float4* pjs = (const float4*)(P + NC * 3 + (size_t)src * 128);
  float4 fi = pif[lane], fj = pjf[lane], si = pis[lane], sj = pjs[lane];
  float4 wf4 = *(const float4*)&wfe[lane * 4];
  float4 ws4 = *(const float4*)&wse[lane * 4];
  float m0 = sigmoid_f(fi.x + fj.x + eV * wf4.x) * softplus_f(si.x + sj.x + eV * ws4.x);
  float m1 = sigmoid_f(fi.y + fj.y + eV * wf4.y) * softplus_f(si.y + sj.y + eV * ws4.y);
  float m2 = sigmoid_f(fi.z + fj.z + eV * wf4.z) * softplus_f(si.z + sj.z + eV * ws4.z);
  float m3 = sigmoid_f(fi.w + fj.w + eV * wf4.w) * softplus_f(si.w + sj.w + eV * ws4.w);
  float* arow = aggr + (size_t)dst * 128 + lane * 4;
  atomicAdd(arow + 0, m0);
  atomicAdd(arow + 1, m1);
  atomicAdd(arow + 2, m2);
  atomicAdd(arow + 3, m3);
}

// ---------------- per-channel sum / sumsq over aggr ----------------------------
__global__ __launch_bounds__(256) void stats_kernel(const float* __restrict__ aggr,
                                                    double* __restrict__ dstats) {
  int tid = threadIdx.x;
  int c = tid & 127, half = tid >> 7;
  int rbase = blockIdx.x * 512;
  float s = 0.f, q = 0.f;
  for (int i = 0; i < 256; ++i) {
    int r = rbase + half + i * 2;
    if (r < NN) {
      float v = aggr[(size_t)r * 128 + c];
      s += v;
      q += v * v;
    }
  }
  __shared__ float shs[256], shq[256];
  shs[tid] = s;
  shq[tid] = q;
  __syncthreads();
  if (tid < 128) {
    double ts = (double)shs[tid] + (double)shs[tid + 128];
    double tq = (double)shq[tid] + (double)shq[tid + 128];
    atomicAdd(&dstats[c], ts);
    atomicAdd(&dstats[128 + c], tq);
  }
}

// ---------------- fold BN into per-channel scale/shift -------------------------
__global__ void bn_params_kernel(const double* __restrict__ dstats,
                                 const float* __restrict__ gamma,
                                 const float* __restrict__ beta,
                                 float* __restrict__ scsh) {
  int c = threadIdx.x;
  double mean = dstats[c] / (double)NN;
  double var = dstats[128 + c] / (double)NN - mean * mean;
  double rs = 1.0 / sqrt(var + 1e-5);
  double sc = (double)gamma[c] * rs;
  scsh[c] = (float)sc;
  scsh[128 + c] = (float)((double)beta[c] - mean * sc);
}

// ---------------- y = 2*out + aggr*scale + shift (in-place on d_out) -----------
__global__ __launch_bounds__(256) void finalize_kernel(const float* __restrict__ outbuf,
                                                       const float* __restrict__ scsh,
                                                       float* __restrict__ dout) {
  __shared__ float sc[128], sh[128];
  int tid = threadIdx.x;
  if (tid < 128) sc[tid] = scsh[tid];
  else sh[tid - 128] = scsh[tid];
  __syncthreads();
  size_t i = (size_t)blockIdx.x * 256 + tid;
  size_t stride = (size_t)gridDim.x * 256;
  const float4* o4 = (const float4*)outbuf;
  float4* d4 = (float4*)dout;
  const size_t n4 = (size_t)NN * 32;
  for (; i < n4; i += stride) {
    int c4 = (int)(i & 31) * 4;
    float4 a = d4[i], o = o4[i];
    float4 r;
    r.x = 2.f * o.x + a.x * sc[c4 + 0] + sh[c4 + 0];
    r.y = 2.f * o.y + a.y * sc[c4 + 1] + sh[c4 + 1];
    r.z = 2.f * o.z + a.z * sc[c4 + 2] + sh[c4 + 2];
    r.w = 2.f * o.w + a.w * sc[c4 + 3] + sh[c4 + 3];
    d4[i] = r;
  }
}

extern "C" void kernel_launch(void* const* d_in, const int* in_sizes, int n_in,
                              void* d_out, int out_size, void* d_ws, size_t ws_size,
                              hipStream_t stream) {
  const float* h         = (const float*)d_in[0];
  const int*   eidx      = (const int*)d_in[1];
  // d_in[2] edge_weight: unused by the reference
  const float* edge_attr = (const float*)d_in[3];
  const float* W0    = (const float*)d_in[4];
  const float* b0    = (const float*)d_in[5];
  const float* Wsh   = (const float*)d_in[6];
  const float* bsh   = (const float*)d_in[7];
  const float* Wf    = (const float*)d_in[8];
  const float* bf    = (const float*)d_in[9];
  const float* Ws    = (const float*)d_in[10];
  const float* bs    = (const float*)d_in[11];
  const float* gamma = (const float*)d_in[12];
  const float* beta  = (const float*)d_in[13];
  float* dout = (float*)d_out;

  char* ws = (char*)d_ws;
  const size_t NCb = (size_t)NN * 128 * 4;  // 25.6 MB
  float*  outbuf = (float*)ws;                         // [NN,128]
  float*  P      = (float*)(ws + NCb);                 // 4 slabs [NN,128]
  float*  ebuf   = (float*)(ws + NCb * 5);             // [EE]
  double* dstats = (double*)(ws + NCb * 5 + (size_t)EE * 4);  // 256 doubles
  float*  scsh   = (float*)((char*)dstats + 256 * 8);         // 256 floats

  // 1. zero aggr (d_out) + stats
  zero_kernel<<<2048, 256, 0, stream>>>((float4*)dout, (float*)dstats);

  // 2. out = softplus(h @ W0 + b0)
  const int gblocks = (NN + 63) / 64;
  gemm128<true, true><<<gblocks, 256, 0, stream>>>(h, W0, b0, outbuf, NN);

  // 3. P slabs: pi_f(+bf), pj_f, pi_s(+bs), pj_s
  gemm128<false, true ><<<gblocks, 256, 0, stream>>>(outbuf, Wf,             bf, P,                       NN);
  gemm128<false, false><<<gblocks, 256, 0, stream>>>(outbuf, Wf + 128 * 128, nullptr, P + (size_t)NN * 128,     NN);
  gemm128<false, true ><<<gblocks, 256, 0, stream>>>(outbuf, Ws,             bs, P + (size_t)NN * 128 * 2, NN);
  gemm128<false, false><<<gblocks, 256, 0, stream>>>(outbuf, Ws + 128 * 128, nullptr, P + (size_t)NN * 128 * 3, NN);

  // 4. e = softplus(edge_attr @ Wsh + bsh)
  edge_e_kernel<<<EE / 16, 256, 0, stream>>>(edge_attr, Wsh, bsh, ebuf);

  // 5. per-edge messages + atomic segment sum into d_out
  edge_msg_kernel<<<EE / 8, 256, 0, stream>>>(eidx, ebuf, P, Wf + 256 * 128, Ws + 256 * 128, dout);

  // 6-8. batch stats, BN fold, finalize
  stats_kernel<<<(NN + 511) / 512, 256, 0, stream>>>(dout, dstats);
  bn_params_kernel<<<1, 128, 0, stream>>>(dstats, gamma, beta, scsh);
  finalize_kernel<<<2048, 256, 0, stream>>>(outbuf, scsh, dout);
}

// Round 3
// 1093.470 us; speedup vs baseline: 1.5948x; 1.5948x over previous
//
#include <hip/hip_runtime.h>
#include <cmath>

#define NN 50000
#define EE 600000

__device__ __forceinline__ float softplus_f(float x) {
  return fmaxf(x, 0.f) + log1pf(__expf(-fabsf(x)));
}
__device__ __forceinline__ float sigmoid_f(float x) {
  return 1.f / (1.f + __expf(-x));
}

// ---------------- zero: deg[] + stats doubles ----------------------------------
__global__ __launch_bounds__(256) void zero_kernel(int* __restrict__ deg,
                                                   float* __restrict__ stats_f) {
  int i = blockIdx.x * 256 + threadIdx.x;
  if (i < NN) deg[i] = 0;
  if (i < 512) stats_f[i] = 0.f;  // 256 doubles
}

// ---------------- GEMM: C[64 rows,128] = act(A@B + bias), K=128 in 2 chunks ----
template <bool ACT, bool HASBIAS>
__global__ __launch_bounds__(256) void gemm128(const float* __restrict__ A,
                                               const float* __restrict__ B,
                                               const float* __restrict__ bias,
                                               float* __restrict__ Cmat,
                                               int nrows) {
  __shared__ float Ash[64][68];
  __shared__ float Bsh[64][128];
  const int tid = threadIdx.x;
  const int row0 = blockIdx.x * 64;
  const int tx = tid & 15, ty = tid >> 4;
  const int r0 = ty * 4, c0 = tx * 4;

  float acc[4][8];
#pragma unroll
  for (int r = 0; r < 4; ++r)
#pragma unroll
    for (int j = 0; j < 8; ++j) acc[r][j] = 0.f;

  for (int kb = 0; kb < 2; ++kb) {
    for (int i = tid; i < 64 * 16; i += 256) {
      int r = i >> 4, k4 = i & 15;
      int gr = row0 + r; if (gr >= nrows) gr = nrows - 1;
      float4 v = ((const float4*)(A + (size_t)gr * 128 + kb * 64))[k4];
      *(float4*)&Ash[r][k4 * 4] = v;
    }
    for (int i = tid; i < 64 * 32; i += 256) {
      int k = i >> 5, c4 = i & 31;
      float4 v = ((const float4*)(B + (size_t)(kb * 64 + k) * 128))[c4];
      *(float4*)&Bsh[k][c4 * 4] = v;
    }
    __syncthreads();
#pragma unroll 4
    for (int k = 0; k < 64; ++k) {
      float aa[4] = {Ash[r0 + 0][k], Ash[r0 + 1][k], Ash[r0 + 2][k], Ash[r0 + 3][k]};
      float4 b0 = *(const float4*)&Bsh[k][c0];
      float4 b1 = *(const float4*)&Bsh[k][c0 + 64];
      float bb[8] = {b0.x, b0.y, b0.z, b0.w, b1.x, b1.y, b1.z, b1.w};
#pragma unroll
      for (int r = 0; r < 4; ++r)
#pragma unroll
        for (int j = 0; j < 8; ++j) acc[r][j] = fmaf(aa[r], bb[j], acc[r][j]);
    }
    __syncthreads();
  }

  float bv[8];
#pragma unroll
  for (int j = 0; j < 8; ++j)
    bv[j] = HASBIAS ? bias[j < 4 ? c0 + j : c0 + 60 + j] : 0.f;
#pragma unroll
  for (int r = 0; r < 4; ++r) {
    int gr = row0 + r0 + r;
    if (gr < nrows) {
      float tmp[8];
#pragma unroll
      for (int j = 0; j < 8; ++j) {
        float v = acc[r][j] + bv[j];
        tmp[j] = ACT ? softplus_f(v) : v;
      }
      *(float4*)(Cmat + (size_t)gr * 128 + c0) = make_float4(tmp[0], tmp[1], tmp[2], tmp[3]);
      *(float4*)(Cmat + (size_t)gr * 128 + c0 + 64) = make_float4(tmp[4], tmp[5], tmp[6], tmp[7]);
    }
  }
}

// ---------------- e = softplus(edge_attr @ Wsh + bsh), 16 lanes per edge -------
__global__ __launch_bounds__(256) void edge_e_kernel(const float* __restrict__ edge_attr,
                                                     const float* __restrict__ Wsh,
                                                     const float* __restrict__ bsh,
                                                     float* __restrict__ ebuf) {
  __shared__ float wsh[128];
  int tid = threadIdx.x;
  if (tid < 128) wsh[tid] = Wsh[tid];
  __syncthreads();
  int wave = tid >> 6, lane = tid & 63;
  int sub = lane >> 4, l16 = lane & 15;
  int edge = (blockIdx.x * 4 + wave) * 4 + sub;
  const float4* row = (const float4*)(edge_attr + (size_t)edge * 128);
  float4 v0 = row[l16], v1 = row[l16 + 16];
  float4 w0 = *(const float4*)&wsh[l16 * 4];
  float4 w1 = *(const float4*)&wsh[64 + l16 * 4];
  float p = v0.x * w0.x + v0.y * w0.y + v0.z * w0.z + v0.w * w0.w +
            v1.x * w1.x + v1.y * w1.y + v1.z * w1.z + v1.w * w1.w;
  p += __shfl_xor(p, 1);
  p += __shfl_xor(p, 2);
  p += __shfl_xor(p, 4);
  p += __shfl_xor(p, 8);
  if (l16 == 0) ebuf[edge] = softplus_f(p + bsh[0]);
}

// ---------------- CSR build: histogram ----------------------------------------
__global__ __launch_bounds__(256) void hist_kernel(const int* __restrict__ eidx,
                                                   int* __restrict__ deg) {
  int e = blockIdx.x * 256 + threadIdx.x;
  if (e < EE) atomicAdd(&deg[eidx[EE + e]], 1);
}

// ---------------- CSR build: single-block exclusive scan -----------------------
__global__ __launch_bounds__(1024) void scan_kernel(const int* __restrict__ deg,
                                                    int* __restrict__ rowptr,
                                                    int* __restrict__ cur) {
  __shared__ int wscan[16];
  __shared__ int chunk_total_sh;
  int tid = threadIdx.x;
  int wid = tid >> 6, lane = tid & 63;
  int running = 0;
  for (int base = 0; base < NN; base += 1024) {
    int i = base + tid;
    int v = (i < NN) ? deg[i] : 0;
    int s = v;  // inclusive scan within wave
#pragma unroll
    for (int off = 1; off < 64; off <<= 1) {
      int t = __shfl_up(s, off);
      if (lane >= off) s += t;
    }
    if (lane == 63) wscan[wid] = s;
    __syncthreads();
    if (wid == 0 && lane < 16) {
      int w = wscan[lane];
#pragma unroll
      for (int off = 1; off < 16; off <<= 1) {
        int t = __shfl_up(w, off);
        if (lane >= off) w += t;
      }
      wscan[lane] = w;  // inclusive scan of wave totals
      if (lane == 15) chunk_total_sh = w;
    }
    __syncthreads();
    int wexcl = (wid == 0) ? 0 : wscan[wid - 1];
    int excl = running + wexcl + (s - v);
    if (i < NN) { rowptr[i] = excl; cur[i] = excl; }
    running += chunk_total_sh;
    __syncthreads();  // protect wscan/chunk_total_sh for next chunk
  }
  if (tid == 0) rowptr[NN] = EE;
}

// ---------------- CSR build: scatter (src, e-value) into dst-sorted order ------
__global__ __launch_bounds__(256) void scatter_kernel(const int* __restrict__ eidx,
                                                      const float* __restrict__ ebuf,
                                                      int* __restrict__ cur,
                                                      int* __restrict__ srcs,
                                                      float* __restrict__ evals) {
  int e = blockIdx.x * 256 + threadIdx.x;
  if (e < EE) {
    int dst = eidx[EE + e];
    int pos = atomicAdd(&cur[dst], 1);
    srcs[pos] = eidx[e];
    evals[pos] = ebuf[e];
  }
}

// ---------------- gather-side aggregation: 32 lanes per node, no atomics -------
// pi_f lives in `pifagg` (== d_out): each group reads its own row once, then
// overwrites that row with the aggregate at the end. No cross-node access.
__global__ __launch_bounds__(256) void aggregate_kernel(const int* __restrict__ rowptr,
                                                        const int* __restrict__ srcs,
                                                        const float* __restrict__ evals,
                                                        float* __restrict__ pifagg,
                                                        const float* __restrict__ Pjf,
                                                        const float* __restrict__ Pis,
                                                        const float* __restrict__ Pjs,
                                                        const float* __restrict__ Wf_e,
                                                        const float* __restrict__ Ws_e) {
  __shared__ float wfe[128], wse[128];
  int tid = threadIdx.x;
  if (tid < 128) wfe[tid] = Wf_e[tid];
  else wse[tid - 128] = Ws_e[tid - 128];
  __syncthreads();
  int slot = tid >> 5, lane = tid & 31;
  int node = blockIdx.x * 8 + slot;   // grid sized exactly: 6250*8 == 50000
  float4 fi = ((const float4*)(pifagg + (size_t)node * 128))[lane];
  float4 si = ((const float4*)(Pis + (size_t)node * 128))[lane];
  float4 wf4 = *(const float4*)&wfe[lane * 4];
  float4 ws4 = *(const float4*)&wse[lane * 4];
  float4 acc = make_float4(0.f, 0.f, 0.f, 0.f);

  int beg = rowptr[node], end = rowptr[node + 1];
  if (beg < end) {
    int src = srcs[beg];
    float eV = evals[beg];
    int k = beg;
    while (true) {
      int knext = k + 1;
      bool more = knext < end;
      int nsrc = 0; float neV = 0.f;
      if (more) { nsrc = srcs[knext]; neV = evals[knext]; }  // prefetch
      float4 fj = ((const float4*)(Pjf + (size_t)src * 128))[lane];
      float4 sj = ((const float4*)(Pjs + (size_t)src * 128))[lane];
      acc.x += sigmoid_f(fi.x + fj.x + eV * wf4.x) * softplus_f(si.x + sj.x + eV * ws4.x);
      acc.y += sigmoid_f(fi.y + fj.y + eV * wf4.y) * softplus_f(si.y + sj.y + eV * ws4.y);
      acc.z += sigmoid_f(fi.z + fj.z + eV * wf4.z) * softplus_f(si.z + sj.z + eV * ws4.z);
      acc.w += sigmoid_f(fi.w + fj.w + eV * wf4.w) * softplus_f(si.w + sj.w + eV * ws4.w);
      if (!more) break;
      src = nsrc; eV = neV; k = knext;
    }
  }
  ((float4*)(pifagg + (size_t)node * 128))[lane] = acc;
}

// ---------------- per-channel sum / sumsq over aggr ----------------------------
__global__ __launch_bounds__(256) void stats_kernel(const float* __restrict__ aggr,
                                                    double* __restrict__ dstats) {
  int tid = threadIdx.x;
  int c = tid & 127, half = tid >> 7;
  int rbase = blockIdx.x * 512;
  float s = 0.f, q = 0.f;
  for (int i = 0; i < 256; ++i) {
    int r = rbase + half + i * 2;
    if (r < NN) {
      float v = aggr[(size_t)r * 128 + c];
      s += v;
      q += v * v;
    }
  }
  __shared__ float shs[256], shq[256];
  shs[tid] = s;
  shq[tid] = q;
  __syncthreads();
  if (tid < 128) {
    double ts = (double)shs[tid] + (double)shs[tid + 128];
    double tq = (double)shq[tid] + (double)shq[tid + 128];
    atomicAdd(&dstats[c], ts);
    atomicAdd(&dstats[128 + c], tq);
  }
}

// ---------------- fold BN into per-channel scale/shift -------------------------
__global__ void bn_params_kernel(const double* __restrict__ dstats,
                                 const float* __restrict__ gamma,
                                 const float* __restrict__ beta,
                                 float* __restrict__ scsh) {
  int c = threadIdx.x;
  double mean = dstats[c] / (double)NN;
  double var = dstats[128 + c] / (double)NN - mean * mean;
  double rs = 1.0 / sqrt(var + 1e-5);
  double sc = (double)gamma[c] * rs;
  scsh[c] = (float)sc;
  scsh[128 + c] = (float)((double)beta[c] - mean * sc);
}

// ---------------- y = 2*out + aggr*scale + shift (in-place on d_out) -----------
__global__ __launch_bounds__(256) void finalize_kernel(const float* __restrict__ outbuf,
                                                       const float* __restrict__ scsh,
                                                       float* __restrict__ dout) {
  __shared__ float sc[128], sh[128];
  int tid = threadIdx.x;
  if (tid < 128) sc[tid] = scsh[tid];
  else sh[tid - 128] = scsh[tid];
  __syncthreads();
  size_t i = (size_t)blockIdx.x * 256 + tid;
  size_t stride = (size_t)gridDim.x * 256;
  const float4* o4 = (const float4*)outbuf;
  float4* d4 = (float4*)dout;
  const size_t n4 = (size_t)NN * 32;
  for (; i < n4; i += stride) {
    int c4 = (int)(i & 31) * 4;
    float4 a = d4[i], o = o4[i];
    float4 r;
    r.x = 2.f * o.x + a.x * sc[c4 + 0] + sh[c4 + 0];
    r.y = 2.f * o.y + a.y * sc[c4 + 1] + sh[c4 + 1];
    r.z = 2.f * o.z + a.z * sc[c4 + 2] + sh[c4 + 2];
    r.w = 2.f * o.w + a.w * sc[c4 + 3] + sh[c4 + 3];
    d4[i] = r;
  }
}

extern "C" void kernel_launch(void* const* d_in, const int* in_sizes, int n_in,
                              void* d_out, int out_size, void* d_ws, size_t ws_size,
                              hipStream_t stream) {
  const float* h         = (const float*)d_in[0];
  const int*   eidx      = (const int*)d_in[1];
  const float* edge_attr = (const float*)d_in[3];
  const float* W0    = (const float*)d_in[4];
  const float* b0    = (const float*)d_in[5];
  const float* Wsh   = (const float*)d_in[6];
  const float* bsh   = (const float*)d_in[7];
  const float* Wf    = (const float*)d_in[8];
  const float* bf    = (const float*)d_in[9];
  const float* Ws    = (const float*)d_in[10];
  const float* bs    = (const float*)d_in[11];
  const float* gamma = (const float*)d_in[12];
  const float* beta  = (const float*)d_in[13];
  float* dout = (float*)d_out;

  // Workspace layout (~110.2 MB). dstats (doubles) placed at an offset that is
  // a multiple of 16 BEFORE any odd-sized int arrays — the round-2 crash was a
  // misaligned global_atomic_add_f64 (dstats landed 4-aligned after rowptr's
  // (NN+1)*4 = 200,004 bytes).
  char* ws = (char*)d_ws;
  const size_t NCb = (size_t)NN * 128 * 4;  // 25.6 MB
  float*  outbuf = (float*)ws;                         // [NN,128]
  float*  Pjf    = (float*)(ws + NCb);                 // [NN,128]
  float*  Pis    = (float*)(ws + NCb * 2);             // [NN,128]
  float*  Pjs    = (float*)(ws + NCb * 3);             // [NN,128]
  char*   p0     = ws + NCb * 4;                       // 102,400,000 (16-aligned)
  float*  ebuf   = (float*)p0;                  p0 += (size_t)EE * 4;        // 16-aligned
  int*    srcs   = (int*)p0;                    p0 += (size_t)EE * 4;
  float*  evals  = (float*)p0;                  p0 += (size_t)EE * 4;
  double* dstats = (double*)p0;                 p0 += 256 * 8;               // 16-aligned ✓
  float*  scsh   = (float*)p0;                  p0 += 256 * 4;
  int*    deg    = (int*)p0;                    p0 += (size_t)NN * 4;
  int*    rowptr = (int*)p0;                    p0 += (size_t)(NN + 1) * 4;
  int*    cur    = (int*)p0;
  float*  Pif    = dout;  // pi_f slab lives in d_out; aggregate overwrites it

  // 1. zero deg + stats
  zero_kernel<<<(NN + 255) / 256, 256, 0, stream>>>(deg, (float*)dstats);

  // 2. out = softplus(h @ W0 + b0)
  const int gblocks = (NN + 63) / 64;
  gemm128<true, true><<<gblocks, 256, 0, stream>>>(h, W0, b0, outbuf, NN);

  // 3. P slabs: pi_f(+bf)->d_out, pj_f, pi_s(+bs), pj_s
  gemm128<false, true ><<<gblocks, 256, 0, stream>>>(outbuf, Wf,             bf,      Pif, NN);
  gemm128<false, false><<<gblocks, 256, 0, stream>>>(outbuf, Wf + 128 * 128, nullptr, Pjf, NN);
  gemm128<false, true ><<<gblocks, 256, 0, stream>>>(outbuf, Ws,             bs,      Pis, NN);
  gemm128<false, false><<<gblocks, 256, 0, stream>>>(outbuf, Ws + 128 * 128, nullptr, Pjs, NN);

  // 4. e = softplus(edge_attr @ Wsh + bsh)
  edge_e_kernel<<<EE / 16, 256, 0, stream>>>(edge_attr, Wsh, bsh, ebuf);

  // 5. CSR build by dst
  hist_kernel<<<(EE + 255) / 256, 256, 0, stream>>>(eidx, deg);
  scan_kernel<<<1, 1024, 0, stream>>>(deg, rowptr, cur);
  scatter_kernel<<<(EE + 255) / 256, 256, 0, stream>>>(eidx, ebuf, cur, srcs, evals);

  // 6. gather-side aggregation (no atomics; writes aggr into d_out)
  aggregate_kernel<<<NN / 8, 256, 0, stream>>>(rowptr, srcs, evals, Pif, Pjf, Pis, Pjs,
                                               Wf + 256 * 128, Ws + 256 * 128);

  // 7-9. batch stats, BN fold, finalize
  stats_kernel<<<(NN + 511) / 512, 256, 0, stream>>>(dout, dstats);
  bn_params_kernel<<<1, 128, 0, stream>>>(dstats, gamma, beta, scsh);
  finalize_kernel<<<2048, 256, 0, stream>>>(outbuf, scsh, dout);
}